// Round 5
// baseline (627.406 us; speedup 1.0000x reference)
//
#include <hip/hip_runtime.h>

// Problem dims
#define TOKS    65536      // 16 * 4096
#define D_IN    512
#define D_E     256
#define NCODES  1024

#define FLAG_CAP 16384
#define TAU      0.05f     // gap threshold for fp32 refinement (~60 sigma of approx err)

using s16x8 = __attribute__((ext_vector_type(8))) short;   // 8 bf16 = 4 VGPRs
using f32x4 = __attribute__((ext_vector_type(4))) float;   // MFMA 16x16 accumulator

__device__ __forceinline__ unsigned short bf16_rne(float x) {
    unsigned u = __float_as_uint(x);
    u += 0x7fffu + ((u >> 16) & 1u);
    return (unsigned short)(u >> 16);
}
__device__ __forceinline__ float bf16_to_f(unsigned short h) {
    return __uint_as_float(((unsigned)h) << 16);
}

// Unpack 8 interleaved (hi<<16|lo) words into separate hi/lo bf16x8 fragments.
__device__ __forceinline__ void unpack_il(uint4 u0, uint4 u1, s16x8& hi, s16x8& lo) {
    union { unsigned u[4]; s16x8 v; } H, L;
    H.u[0] = (u0.y & 0xffff0000u) | (u0.x >> 16);
    H.u[1] = (u0.w & 0xffff0000u) | (u0.z >> 16);
    H.u[2] = (u1.y & 0xffff0000u) | (u1.x >> 16);
    H.u[3] = (u1.w & 0xffff0000u) | (u1.z >> 16);
    L.u[0] = (u0.y << 16) | (u0.x & 0xffffu);
    L.u[1] = (u0.w << 16) | (u0.z & 0xffffu);
    L.u[2] = (u1.y << 16) | (u1.x & 0xffffu);
    L.u[3] = (u1.w << 16) | (u1.z & 0xffffu);
    hi = H.v; lo = L.v;
}

// ---------------------------------------------------------------------------
// Row squared-norm on fp32 rows of 256 (codebook -> cnorm). One wave/row.
// ---------------------------------------------------------------------------
__global__ __launch_bounds__(256) void rownorm_kernel(
        const float* __restrict__ src, float* __restrict__ dst) {
    int row  = blockIdx.x * 4 + (threadIdx.x >> 6);
    int lane = threadIdx.x & 63;
    float4 v = *(const float4*)(src + (long)row * 256 + lane * 4);
    float s = v.x * v.x + v.y * v.y + v.z * v.z + v.w * v.w;
    #pragma unroll
    for (int off = 32; off; off >>= 1) s += __shfl_xor(s, off, 64);
    if (lane == 0) dst[row] = s;
}

// ---------------------------------------------------------------------------
// fp32 -> (hi, lo) bf16 planes. hi = rne(x), lo = rne(x - hi): x to ~2^-17 rel.
// ---------------------------------------------------------------------------
__global__ __launch_bounds__(256) void split_kernel(
        const float* __restrict__ src, unsigned short* __restrict__ hi,
        unsigned short* __restrict__ lo, int n) {
    int i = blockIdx.x * 256 + threadIdx.x;
    if (i < n) {
        float x = src[i];
        unsigned short hb = bf16_rne(x);
        hi[i] = hb;
        lo[i] = bf16_rne(x - bf16_to_f(hb));
    }
}

// ---------------------------------------------------------------------------
// cb_up = cb @ w_up^T in EXACT fp32: [1024,256] x [512,256]^T -> [1024,512].
// ---------------------------------------------------------------------------
__global__ __launch_bounds__(256) void cb_up_kernel(
        const float* __restrict__ cb, const float* __restrict__ w_up,
        float* __restrict__ cb_up) {
    __shared__ float cbs4[4][256];
    const int tid = threadIdx.x;
    const int r0  = blockIdx.x * 4;
    #pragma unroll
    for (int r = 0; r < 4; ++r) cbs4[r][tid] = cb[(long)(r0 + r) * 256 + tid];
    __syncthreads();
    float acc[4][2] = {};
    const float* wa = w_up + (long)tid * 256;
    const float* wb = w_up + (long)(tid + 256) * 256;
    #pragma unroll 4
    for (int k = 0; k < 256; k += 4) {
        float4 a = *(const float4*)(wa + k);
        float4 b = *(const float4*)(wb + k);
        #pragma unroll
        for (int r = 0; r < 4; ++r) {
            float4 c = *(const float4*)&cbs4[r][k];
            acc[r][0] += a.x * c.x + a.y * c.y + a.z * c.z + a.w * c.w;
            acc[r][1] += b.x * c.x + b.y * c.y + b.z * c.z + b.w * c.w;
        }
    }
    #pragma unroll
    for (int r = 0; r < 4; ++r) {
        cb_up[(long)(r0 + r) * 512 + tid]       = acc[r][0];
        cb_up[(long)(r0 + r) * 512 + tid + 256] = acc[r][1];
    }
}

// ---------------------------------------------------------------------------
// z_out[tok] = cb_up[code[tok]] : pure gather, HBM-write-bound (~128 MB).
// ---------------------------------------------------------------------------
__global__ __launch_bounds__(256) void gather_kernel(
        const float4* __restrict__ cb_up4, const int* __restrict__ code_i,
        float4* __restrict__ out4) {
    const int base = blockIdx.x * 1024 + threadIdx.x;
    #pragma unroll
    for (int j = 0; j < 4; ++j) {
        int g   = base + j * 256;
        int tok = g >> 7;          // 128 float4 per 512-float row
        int col = g & 127;
        out4[g] = cb_up4[(long)code_i[tok] * 128 + col];
    }
}

// ---------------------------------------------------------------------------
// GEMM1 via bf16x3 MFMA: z_e = z @ w_down^T  [65536,512] x [256,512]^T.
// OCCUPANCY RESTRUCTURE: 64 tokens/block (grid 1024 = 4 blocks/CU), wave
// owns 16 tokens x all 256 dims (acc 64 VGPRs), launch_bounds(256,4) to
// cap VGPR <= 128 -> 16 waves/CU (was grid-capped at 8).
// w_down planes single-buffer LDS-staged per 32-k step (32 KB, 2 barriers).
// z fp32 read once, split hi/lo bf16 in-register (exact-trunc hi).
// Epilogue: interleaved z_e planes (hi<<16|lo) + fused znorm.
// ---------------------------------------------------------------------------
__global__ __launch_bounds__(256, 4) void gemm_down_mfma_kernel(
        const float* __restrict__ z, const unsigned short* __restrict__ wd_hi,
        const unsigned short* __restrict__ wd_lo, unsigned* __restrict__ ze_il,
        float* __restrict__ znorm) {
    __shared__ __align__(16) unsigned short wds[2][256][32];   // 32 KB

    const int tid  = threadIdx.x;
    const int w    = tid >> 6;
    const int lane = tid & 63;
    const int lr   = lane & 15;
    const int lg   = lane >> 4;
    const int t0   = blockIdx.x * 64 + w * 16;

    f32x4 acc[16] = {};   // [n-tile] : 16 tokens x 256 dims per wave

    #pragma unroll 1
    for (int ks = 0; ks < 16; ++ks) {        // K = 512 in steps of 32
        __syncthreads();                      // prev compute done reading wds
        {   // stage both wd planes for this k-step: 2048 16B units / 256 thr
            #pragma unroll
            for (int i = 0; i < 8; ++i) {
                const int j = i * 256 + tid;
                const int p = j >> 10, rw = (j >> 2) & 255, sub = j & 3;
                const s16x8 v = *(const s16x8*)((p ? wd_lo : wd_hi)
                                                + (long)rw * 512 + ks * 32 + sub * 8);
                *(s16x8*)((unsigned short*)wds + j * 8) = v;
            }
        }

        // A fragments: z fp32 -> hi (exact truncation) + lo (rne of remainder)
        s16x8 ah, al;
        {
            const float* zp = z + (long)(t0 + lr) * 512 + ks * 32 + lg * 8;
            float4 x0 = *(const float4*)zp;
            float4 x1 = *(const float4*)(zp + 4);
            float xs[8] = {x0.x, x0.y, x0.z, x0.w, x1.x, x1.y, x1.z, x1.w};
            #pragma unroll
            for (int j = 0; j < 8; ++j) {
                unsigned hb = __float_as_uint(xs[j]) & 0xffff0000u;
                float rem = xs[j] - __uint_as_float(hb);
                ah[j] = (short)(hb >> 16);
                al[j] = (short)bf16_rne(rem);
            }
        }
        __syncthreads();                      // staging complete

        #pragma unroll
        for (int nt = 0; nt < 16; ++nt) {
            const s16x8 bh = *(const s16x8*)&wds[0][nt * 16 + lr][lg * 8];
            const s16x8 bl = *(const s16x8*)&wds[1][nt * 16 + lr][lg * 8];
            acc[nt] = __builtin_amdgcn_mfma_f32_16x16x32_bf16(al, bh, acc[nt], 0, 0, 0);
            acc[nt] = __builtin_amdgcn_mfma_f32_16x16x32_bf16(ah, bl, acc[nt], 0, 0, 0);
            acc[nt] = __builtin_amdgcn_mfma_f32_16x16x32_bf16(ah, bh, acc[nt], 0, 0, 0);
        }
    }

    // ---- epilogue: interleaved plane write + fused znorm ----
    float ns[4] = {0.f, 0.f, 0.f, 0.f};
    #pragma unroll
    for (int nt = 0; nt < 16; ++nt)
        #pragma unroll
        for (int r = 0; r < 4; ++r) {
            float x = acc[nt][r];
            ns[r] += x * x;
            unsigned short hb = bf16_rne(x);
            unsigned short lb = bf16_rne(x - bf16_to_f(hb));
            ze_il[(long)(t0 + lg * 4 + r) * 256 + nt * 16 + lr] =
                ((unsigned)hb << 16) | lb;
        }
    #pragma unroll
    for (int r = 0; r < 4; ++r) {
        float s = ns[r];
        s += __shfl_xor(s, 1, 64);
        s += __shfl_xor(s, 2, 64);
        s += __shfl_xor(s, 4, 64);
        s += __shfl_xor(s, 8, 64);
        if (lr == 0) znorm[t0 + lg * 4 + r] = s;
    }
}

// ---------------------------------------------------------------------------
// Fused distance + argmin via bf16x3 MFMA (16x16x32).
// OCCUPANCY RESTRUCTURE: 64 tokens/block (grid 1024 = 4 blocks/CU), wave
// owns 16 tokens (A-frags 64 VGPRs), launch_bounds(256,4) -> 16 waves/CU.
// z_e read once into full-K register fragments; codebook chunks (64 codes x
// 128 k) staged in LDS, padded row stride 136 shorts. Top-2 + flags.
// ---------------------------------------------------------------------------
__global__ __launch_bounds__(256, 4) void argmin_mfma_kernel(
        const unsigned* __restrict__ ze_il,
        const unsigned short* __restrict__ cb_hi, const unsigned short* __restrict__ cb_lo,
        const float* __restrict__ cnorm, const float* __restrict__ znorm,
        int* __restrict__ code_i, float* __restrict__ code_f,
        float* __restrict__ loss_acc, int* __restrict__ flag_cnt,
        int4* __restrict__ flag_list) {
    __shared__ __align__(16) unsigned short cbs[2][64][136];   // 34 KB, padded stride

    const int tid  = threadIdx.x;
    const int w    = tid >> 6;
    const int lane = tid & 63;
    const int lr   = lane & 15;      // row/col within 16-tile
    const int lg   = lane >> 4;      // k-group (0..3)
    const int t0   = blockIdx.x * 64;

    // ---- load A fragments once: 1 token-tile x 8 k-steps x {hi,lo} ----
    s16x8 ah[8], al[8];
    {
        const unsigned* pz = ze_il + (long)(t0 + w * 16 + lr) * 256 + lg * 8;
        #pragma unroll
        for (int ks = 0; ks < 8; ++ks) {
            uint4 u0 = *(const uint4*)(pz + ks * 32);
            uint4 u1 = *(const uint4*)(pz + ks * 32 + 4);
            unpack_il(u0, u1, ah[ks], al[ks]);
        }
    }

    const int lane_base = lr * 136 + lg * 8;   // shorts; rest static offsets

    float d1[4], d2[4];
    int   i1[4], i2[4];
    #pragma unroll
    for (int s = 0; s < 4; ++s) { d1[s] = 3.4e38f; d2[s] = 3.4e38f; i1[s] = 0; i2[s] = 0; }

    #pragma unroll 1
    for (int c = 0; c < 16; ++c) {           // 64-code chunks
        const int c0 = c * 64;
        f32x4 acc[4] = {};

        #pragma unroll
        for (int kc = 0; kc < 2; ++kc) {     // 128-k chunks
            __syncthreads();
            {   // stage cb chunk: wave-pair q picks plane, half the 16B units
                const int r = tid & 63, q = tid >> 6;
                const unsigned short* src = (q & 2 ? cb_lo : cb_hi)
                                            + (c0 + r) * 256 + kc * 128 + (q & 1) * 64;
                unsigned short* dst = &cbs[q >> 1][r][0] + (q & 1) * 64;
                #pragma unroll
                for (int i = 0; i < 8; ++i)
                    *(s16x8*)(dst + i * 8) = *(const s16x8*)(src + i * 8);
            }
            __syncthreads();

            #pragma unroll
            for (int k4 = 0; k4 < 4; ++k4) {
                const int ks = kc * 4 + k4;                 // A reg index (static)
                #pragma unroll
                for (int nt = 0; nt < 4; ++nt) {
                    const int off = lane_base + nt * 2176 + k4 * 32;   // shorts
                    const s16x8 bh = *(const s16x8*)(&cbs[0][0][0] + off);
                    const s16x8 bl = *(const s16x8*)(&cbs[1][0][0] + off);
                    acc[nt] = __builtin_amdgcn_mfma_f32_16x16x32_bf16(al[ks], bh, acc[nt], 0, 0, 0);
                    acc[nt] = __builtin_amdgcn_mfma_f32_16x16x32_bf16(ah[ks], bl, acc[nt], 0, 0, 0);
                    acc[nt] = __builtin_amdgcn_mfma_f32_16x16x32_bf16(ah[ks], bh, acc[nt], 0, 0, 0);
                }
            }
        }

        // ---- fold chunk into running top-2 (codes ascend -> strict < keeps first) ----
        #pragma unroll
        for (int nt = 0; nt < 4; ++nt) {
            const int idx = c0 + nt * 16 + lr;
            const float cn = cnorm[idx];
            #pragma unroll
            for (int r = 0; r < 4; ++r) {
                float d = cn - 2.0f * acc[nt][r];
                if (d < d1[r])      { d2[r] = d1[r]; i2[r] = i1[r]; d1[r] = d; i1[r] = idx; }
                else if (d < d2[r]) { d2[r] = d;     i2[r] = idx; }
            }
        }
    }

    // ---- cross-lane top-2 merge over the 16 code columns ----
    #pragma unroll
    for (int off = 1; off <= 8; off <<= 1) {
        #pragma unroll
        for (int s = 0; s < 4; ++s) {
            float od1 = __shfl_xor(d1[s], off, 64);
            int   oi1 = __shfl_xor(i1[s], off, 64);
            float od2 = __shfl_xor(d2[s], off, 64);
            int   oi2 = __shfl_xor(i2[s], off, 64);
            bool take = (od1 < d1[s]) || (od1 == d1[s] && oi1 < i1[s]);
            float w1 = take ? od1 : d1[s];  int wi1 = take ? oi1 : i1[s];
            float l1 = take ? d1[s] : od1;  int li1 = take ? i1[s] : oi1;   // loser of firsts
            float w2 = take ? od2 : d2[s];  int wi2 = take ? oi2 : i2[s];   // winner's second
            bool t2 = (l1 < w2) || (l1 == w2 && li1 < wi2);
            d1[s] = w1; i1[s] = wi1;
            d2[s] = t2 ? l1 : w2;
            i2[s] = t2 ? li1 : wi2;
        }
    }

    // ---- write: lanes lr==0 own tokens (w*16 + lg*4 + s) ----
    if (lr == 0) {
        float lsum = 0.0f;
        #pragma unroll
        for (int s = 0; s < 4; ++s) {
            const int tok = t0 + w * 16 + lg * 4 + s;
            code_i[tok] = i1[s];
            code_f[tok] = (float)i1[s];
            const float rec = d1[s] + znorm[tok];
            lsum += rec;
            if (d2[s] - d1[s] < TAU) {
                int slot = atomicAdd(flag_cnt, 1);
                if (slot < FLAG_CAP)
                    flag_list[slot] = make_int4(tok, i1[s], i2[s], __float_as_int(rec));
            }
        }
        atomicAdd(loss_acc + (t0 >> 12), lsum);   // 64-tok block never straddles a batch
    }
}

// ---------------------------------------------------------------------------
// Exact fp32 refinement for near-tie tokens: recompute z_e row from z@w_down
// in fp32, re-decide best-of-two with first-index tie-break, patch loss.
// ---------------------------------------------------------------------------
__global__ __launch_bounds__(256) void refine_kernel(
        const float* __restrict__ z, const float* __restrict__ w_down,
        const float* __restrict__ cb, const int* __restrict__ flag_cnt,
        const int4* __restrict__ flag_list, int* __restrict__ code_i,
        float* __restrict__ code_f, float* __restrict__ loss_acc) {
    __shared__ float zrow[512];
    __shared__ float redA[4], redB[4];
    const int tid = threadIdx.x;
    int n = *flag_cnt;
    if (n > FLAG_CAP) n = FLAG_CAP;

    for (int it = blockIdx.x; it < n; it += gridDim.x) {
        const int4 f = flag_list[it];
        const int tok = f.x, ia = f.y, ib = f.z;
        __syncthreads();
        zrow[tid]       = z[(long)tok * 512 + tid];
        zrow[tid + 256] = z[(long)tok * 512 + 256 + tid];
        __syncthreads();

        // thread e computes z_e[e] = dot(w_down[e], zrow) in fp32
        float s = 0.0f;
        const float* wr = w_down + (long)tid * 512;
        #pragma unroll 4
        for (int k = 0; k < 512; k += 4) {
            float4 a = *(const float4*)(wr + k);
            s += a.x * zrow[k] + a.y * zrow[k + 1] + a.z * zrow[k + 2] + a.w * zrow[k + 3];
        }
        float da = s - cb[(long)ia * 256 + tid]; da *= da;
        float db = s - cb[(long)ib * 256 + tid]; db *= db;
        #pragma unroll
        for (int off = 32; off; off >>= 1) {
            da += __shfl_xor(da, off, 64);
            db += __shfl_xor(db, off, 64);
        }
        if ((tid & 63) == 0) { redA[tid >> 6] = da; redB[tid >> 6] = db; }
        __syncthreads();
        if (tid == 0) {
            float ea = redA[0] + redA[1] + redA[2] + redA[3];
            float eb = redB[0] + redB[1] + redB[2] + redB[3];
            float ebest = ea; int ibest = ia;
            if (eb < ea || (eb == ea && ib < ia)) { ebest = eb; ibest = ib; }
            if (ibest != ia) { code_i[tok] = ibest; code_f[tok] = (float)ibest; }
            atomicAdd(loss_acc + (tok >> 12), ebest - __int_as_float(f.w));
        }
    }
}

// ---------------------------------------------------------------------------
// Scale summed losses by 1/(4096*256) and write both loss outputs.
// ---------------------------------------------------------------------------
__global__ void finalize_kernel(const float* __restrict__ loss_acc,
                                float* __restrict__ out_losses) {
    int i = threadIdx.x;
    if (i < 16) {
        float v = loss_acc[i] * (1.0f / 1048576.0f);
        out_losses[i]      = v;   // commitment_loss
        out_losses[16 + i] = v;   // codebook_loss (same forward value)
    }
}

// ---------------------------------------------------------------------------
extern "C" void kernel_launch(void* const* d_in, const int* in_sizes, int n_in,
                              void* d_out, int out_size, void* d_ws, size_t ws_size,
                              hipStream_t stream) {
    const float* z      = (const float*)d_in[0];  // [16,4096,512]
    const float* cb     = (const float*)d_in[1];  // [1024,256]
    const float* w_down = (const float*)d_in[2];  // [256,512]
    const float* w_up   = (const float*)d_in[3];  // [512,256]

    float* out        = (float*)d_out;
    float* z_out      = out;                       // 33554432 floats
    float* out_losses = out + 33554432;            // 16 + 16 floats
    float* code_f     = out + 33554464;            // 65536 floats

    // z_e interleaved planes (hi<<16|lo, 64 MiB) live inside the not-yet-
    // written z_out region; fully consumed by argmin before gather writes.
    unsigned* ze_il = (unsigned*)d_out;

    char* ws = (char*)d_ws;
    unsigned short* cb_hi = (unsigned short*)(ws);             // 512 KiB
    unsigned short* cb_lo = (unsigned short*)(ws + 524288);    // 512 KiB
    unsigned short* wd_hi = (unsigned short*)(ws + 1048576);   // 256 KiB
    unsigned short* wd_lo = (unsigned short*)(ws + 1310720);   // 256 KiB
    int*   code_i    = (int*)  (ws + 1572864);                 // 256 KiB
    float* cnorm     = (float*)(ws + 1835008);                 // 4 KiB
    float* znorm     = (float*)(ws + 1839104);                 // 256 KiB
    int4*  flag_list = (int4*) (ws + 2101248);                 // 256 KiB
    float* cb_up     = (float*)(ws + 2363392);                 // 2 MiB
    float* loss_acc  = (float*)(ws + 4460544);                 // 64 B
    int*   flag_cnt  = (int*)  (ws + 4460608);                 // 4 B

    hipMemsetAsync(ws + 4460544, 0, 128, stream);

    // codebook row norms (fp32)
    rownorm_kernel<<<NCODES / 4, 256, 0, stream>>>(cb, cnorm);

    // bf16 hi/lo planes of codebook and w_down
    split_kernel<<<1024, 256, 0, stream>>>(cb, cb_hi, cb_lo, NCODES * D_E);
    split_kernel<<<512, 256, 0, stream>>>(w_down, wd_hi, wd_lo, D_E * D_IN);

    // exact fp32 up-projection of the whole codebook (replaces GEMM2)
    cb_up_kernel<<<NCODES / 4, 256, 0, stream>>>(cb, w_up, cb_up);

    // GEMM1 (MFMA bf16x3, 64 tok/block, 4 blocks/CU): z_e planes + znorm
    gemm_down_mfma_kernel<<<TOKS / 64, 256, 0, stream>>>(
        z, wd_hi, wd_lo, ze_il, znorm);

    // distances + argmin + losses (64 tok/block, 4 blocks/CU)
    argmin_mfma_kernel<<<TOKS / 64, 256, 0, stream>>>(
        ze_il, cb_hi, cb_lo, cnorm, znorm, code_i, code_f, loss_acc,
        flag_cnt, flag_list);

    // exact fp32 re-decision for near-tie tokens
    refine_kernel<<<256, 256, 0, stream>>>(z, w_down, cb, flag_cnt, flag_list,
                                           code_i, code_f, loss_acc);

    // z_out = cb_up[code] : pure gather, write-bound
    gather_kernel<<<TOKS * 512 / 4 / 1024, 256, 0, stream>>>(
        (const float4*)cb_up, code_i, (float4*)z_out);

    finalize_kernel<<<1, 64, 0, stream>>>(loss_acc, out_losses);
}

// Round 7
// 469.828 us; speedup vs baseline: 1.3354x; 1.3354x over previous
//
#include <hip/hip_runtime.h>

// Problem dims
#define TOKS    65536      // 16 * 4096
#define D_IN    512
#define D_E     256
#define NCODES  1024

#define FLAG_CAP 16384
#define TAU      0.05f     // gap threshold for fp32 refinement (~60 sigma of approx err)

using s16x8  = __attribute__((ext_vector_type(8)))  short;   // 8 bf16 = 4 VGPRs
using f32x4  = __attribute__((ext_vector_type(4)))  float;
using f32x16 = __attribute__((ext_vector_type(16))) float;   // 32x32 MFMA accumulator

__device__ __forceinline__ unsigned short bf16_rne(float x) {
    unsigned u = __float_as_uint(x);
    u += 0x7fffu + ((u >> 16) & 1u);
    return (unsigned short)(u >> 16);
}
__device__ __forceinline__ float bf16_to_f(unsigned short h) {
    return __uint_as_float(((unsigned)h) << 16);
}

// Unpack 8 interleaved (hi<<16|lo) words into separate hi/lo bf16x8 fragments.
__device__ __forceinline__ void unpack_il(uint4 u0, uint4 u1, s16x8& hi, s16x8& lo) {
    union { unsigned u[4]; s16x8 v; } H, L;
    H.u[0] = (u0.y & 0xffff0000u) | (u0.x >> 16);
    H.u[1] = (u0.w & 0xffff0000u) | (u0.z >> 16);
    H.u[2] = (u1.y & 0xffff0000u) | (u1.x >> 16);
    H.u[3] = (u1.w & 0xffff0000u) | (u1.z >> 16);
    L.u[0] = (u0.y << 16) | (u0.x & 0xffffu);
    L.u[1] = (u0.w << 16) | (u0.z & 0xffffu);
    L.u[2] = (u1.y << 16) | (u1.x & 0xffffu);
    L.u[3] = (u1.w << 16) | (u1.z & 0xffffu);
    hi = H.v; lo = L.v;
}

// ---------------------------------------------------------------------------
// Row squared-norm on fp32 rows of 256 (codebook -> cnorm). One wave/row.
// ---------------------------------------------------------------------------
__global__ __launch_bounds__(256) void rownorm_kernel(
        const float* __restrict__ src, float* __restrict__ dst) {
    int row  = blockIdx.x * 4 + (threadIdx.x >> 6);
    int lane = threadIdx.x & 63;
    float4 v = *(const float4*)(src + (long)row * 256 + lane * 4);
    float s = v.x * v.x + v.y * v.y + v.z * v.z + v.w * v.w;
    #pragma unroll
    for (int off = 32; off; off >>= 1) s += __shfl_xor(s, off, 64);
    if (lane == 0) dst[row] = s;
}

// ---------------------------------------------------------------------------
// fp32 -> (hi, lo) bf16 planes. hi = rne(x), lo = rne(x - hi): x to ~2^-17 rel.
// ---------------------------------------------------------------------------
__global__ __launch_bounds__(256) void split_kernel(
        const float* __restrict__ src, unsigned short* __restrict__ hi,
        unsigned short* __restrict__ lo, int n) {
    int i = blockIdx.x * 256 + threadIdx.x;
    if (i < n) {
        float x = src[i];
        unsigned short hb = bf16_rne(x);
        hi[i] = hb;
        lo[i] = bf16_rne(x - bf16_to_f(hb));
    }
}

// ---------------------------------------------------------------------------
// cb_up = cb @ w_up^T in EXACT fp32: [1024,256] x [512,256]^T -> [1024,512].
// ---------------------------------------------------------------------------
__global__ __launch_bounds__(256) void cb_up_kernel(
        const float* __restrict__ cb, const float* __restrict__ w_up,
        float* __restrict__ cb_up) {
    __shared__ float cbs4[4][256];
    const int tid = threadIdx.x;
    const int r0  = blockIdx.x * 4;
    #pragma unroll
    for (int r = 0; r < 4; ++r) cbs4[r][tid] = cb[(long)(r0 + r) * 256 + tid];
    __syncthreads();
    float acc[4][2] = {};
    const float* wa = w_up + (long)tid * 256;
    const float* wb = w_up + (long)(tid + 256) * 256;
    #pragma unroll 4
    for (int k = 0; k < 256; k += 4) {
        float4 a = *(const float4*)(wa + k);
        float4 b = *(const float4*)(wb + k);
        #pragma unroll
        for (int r = 0; r < 4; ++r) {
            float4 c = *(const float4*)&cbs4[r][k];
            acc[r][0] += a.x * c.x + a.y * c.y + a.z * c.z + a.w * c.w;
            acc[r][1] += b.x * c.x + b.y * c.y + b.z * c.z + b.w * c.w;
        }
    }
    #pragma unroll
    for (int r = 0; r < 4; ++r) {
        cb_up[(long)(r0 + r) * 512 + tid]       = acc[r][0];
        cb_up[(long)(r0 + r) * 512 + tid + 256] = acc[r][1];
    }
}

// ---------------------------------------------------------------------------
// z_out[tok] = cb_up[code[tok]] : pure gather, HBM-write-bound (~128 MB).
// ---------------------------------------------------------------------------
__global__ __launch_bounds__(256) void gather_kernel(
        const float4* __restrict__ cb_up4, const int* __restrict__ code_i,
        float4* __restrict__ out4) {
    const int base = blockIdx.x * 1024 + threadIdx.x;
    #pragma unroll
    for (int j = 0; j < 4; ++j) {
        int g   = base + j * 256;
        int tok = g >> 7;          // 128 float4 per 512-float row
        int col = g & 127;
        out4[g] = cb_up4[(long)code_i[tok] * 128 + col];
    }
}

// ---------------------------------------------------------------------------
// GEMM1 via bf16x3 32x32x16 MFMA: z_e = z @ w_down^T.
// Block = 4 waves x 32 tokens = 128 tokens; grid 512 (2 blocks/CU).
// A = z (m = lane&31 = token, k = 8*(lane>>5)+elem), split hi/lo in-register.
// B = w_down planes, k-major LDS tiles (16-k stages, double-buffered, T14
// issue-early/write-late, 1 barrier/stage). 3 MFMA per 2 ds_read_b128 ->
// LDS:MFMA 1:1 (was 1.6:1 with 16x16).
// Epilogue: interleaved z_e planes (hi<<16|lo, coalesced dwords) + znorm.
// ---------------------------------------------------------------------------
__global__ __launch_bounds__(256, 2) void gemm_down_mfma_kernel(
        const float* __restrict__ z, const unsigned short* __restrict__ wd_hi,
        const unsigned short* __restrict__ wd_lo, unsigned* __restrict__ ze_il,
        float* __restrict__ znorm) {
    __shared__ s16x8 wds[2][2][2][256];   // [buf][plane][kgroup][row] = 32 KB

    const int tid  = threadIdx.x;
    const int w    = tid >> 6;
    const int lane = tid & 63;
    const int li   = lane & 31;      // token within wave tile / B row
    const int h    = lane >> 5;      // k-half
    const int t0w  = blockIdx.x * 128 + w * 32;

    f32x16 acc[8] = {};              // 8 n-tiles of 32 dims = 256

    // prologue: stage ks=0 directly; prefetch z for ks=0
    #pragma unroll
    for (int i = 0; i < 4; ++i) {
        const int j = i * 256 + tid;             // 1024 16B units
        const int p = j >> 9, jj = j & 511, row = jj >> 1, kg = jj & 1;
        wds[0][p][kg][row] = *(const s16x8*)((p ? wd_lo : wd_hi) + row * 512 + kg * 8);
    }
    const float* zrow = z + (long)(t0w + li) * 512 + h * 8;
    float4 zx0 = *(const float4*)(zrow);
    float4 zx1 = *(const float4*)(zrow + 4);
    __syncthreads();

    #pragma unroll 1
    for (int ks = 0; ks < 32; ++ks) {            // K = 512 in 16-k stages
        const int b = ks & 1;
        const bool more = (ks < 31);

        // issue next-stage loads early (hide L2/HBM latency under MFMA)
        s16x8 stg[4];
        float4 nx0, nx1;
        if (more) {
            #pragma unroll
            for (int i = 0; i < 4; ++i) {
                const int j = i * 256 + tid;
                const int p = j >> 9, jj = j & 511, row = jj >> 1, kg = jj & 1;
                stg[i] = *(const s16x8*)((p ? wd_lo : wd_hi)
                                         + row * 512 + (ks + 1) * 16 + kg * 8);
            }
            nx0 = *(const float4*)(zrow + (ks + 1) * 16);
            nx1 = *(const float4*)(zrow + (ks + 1) * 16 + 4);
        }

        // split current z 8-elem fragment to hi/lo bf16
        s16x8 ah, al;
        {
            float xs[8] = {zx0.x, zx0.y, zx0.z, zx0.w, zx1.x, zx1.y, zx1.z, zx1.w};
            #pragma unroll
            for (int j = 0; j < 8; ++j) {
                unsigned hb = __float_as_uint(xs[j]) & 0xffff0000u;
                float rem = xs[j] - __uint_as_float(hb);
                ah[j] = (short)(hb >> 16);
                al[j] = (short)bf16_rne(rem);
            }
        }

        #pragma unroll
        for (int nt = 0; nt < 8; ++nt) {
            const s16x8 bh = wds[b][0][h][nt * 32 + li];
            const s16x8 bl = wds[b][1][h][nt * 32 + li];
            acc[nt] = __builtin_amdgcn_mfma_f32_32x32x16_bf16(al, bh, acc[nt], 0, 0, 0);
            acc[nt] = __builtin_amdgcn_mfma_f32_32x32x16_bf16(ah, bl, acc[nt], 0, 0, 0);
            acc[nt] = __builtin_amdgcn_mfma_f32_32x32x16_bf16(ah, bh, acc[nt], 0, 0, 0);
        }

        if (more) {
            #pragma unroll
            for (int i = 0; i < 4; ++i) {
                const int j = i * 256 + tid;
                const int p = j >> 9, jj = j & 511, row = jj >> 1, kg = jj & 1;
                wds[b ^ 1][p][kg][row] = stg[i];
            }
            zx0 = nx0; zx1 = nx1;
        }
        __syncthreads();
    }

    // ---- epilogue: interleaved z_e planes + fused znorm ----
    float ns[16];
    #pragma unroll
    for (int r = 0; r < 16; ++r) ns[r] = 0.0f;
    #pragma unroll
    for (int nt = 0; nt < 8; ++nt)
        #pragma unroll
        for (int r = 0; r < 16; ++r) {
            float x = acc[nt][r];
            ns[r] += x * x;
            unsigned short hb = bf16_rne(x);
            unsigned short lb = bf16_rne(x - bf16_to_f(hb));
            const int trow = (r & 3) + 8 * (r >> 2) + 4 * h;
            ze_il[(long)(t0w + trow) * 256 + nt * 32 + li] = ((unsigned)hb << 16) | lb;
        }
    #pragma unroll
    for (int r = 0; r < 16; ++r) {
        float s = ns[r];
        s += __shfl_xor(s, 1, 64);
        s += __shfl_xor(s, 2, 64);
        s += __shfl_xor(s, 4, 64);
        s += __shfl_xor(s, 8, 64);
        s += __shfl_xor(s, 16, 64);
        if (li == 0) znorm[t0w + (r & 3) + 8 * (r >> 2) + 4 * h] = s;
    }
}

// ---------------------------------------------------------------------------
// Fused distance + argmin via bf16x3 32x32x16 MFMA, SWAPPED operands:
// A = codebook (m = code), B = z_e (n = token) -> D col = TOKEN: each lane
// tracks top-2 for ONE token in 4 VGPRs; single shfl_xor(32) merge at end.
// Block = 4 waves x 32 tokens = 128 tokens; grid 512 (2 blocks/CU).
// z_e held in registers full-K (128 VGPRs). Codebook chunks (64 codes x
// 128 k x 2 planes) k-major in LDS, code^kgroup XOR swizzle -> conflict
// floor on both ds_write and ds_read. Double-buffered, T14, 1 barrier/stage.
// ---------------------------------------------------------------------------
__global__ __launch_bounds__(256, 2) void argmin_mfma_kernel(
        const unsigned* __restrict__ ze_il,
        const unsigned short* __restrict__ cb_hi, const unsigned short* __restrict__ cb_lo,
        const float* __restrict__ cnorm, const float* __restrict__ znorm,
        int* __restrict__ code_i, float* __restrict__ code_f,
        float* __restrict__ loss_acc, int* __restrict__ flag_cnt,
        int4* __restrict__ flag_list) {
    __shared__ s16x8 cbs[2][2][16][64];   // [buf][plane][kgroup][code^kg] = 64 KB

    const int tid  = threadIdx.x;
    const int w    = tid >> 6;
    const int lane = tid & 63;
    const int li   = lane & 31;      // token within wave tile (B n-index)
    const int h    = lane >> 5;      // k-half
    const int t0w  = blockIdx.x * 128 + w * 32;
    const int tok  = t0w + li;

    // ---- stage 0 (c=0, kc=0) into buf0 ----
    #pragma unroll
    for (int i = 0; i < 8; ++i) {
        const int j = i * 256 + tid;             // 2048 16B units
        const int p = j >> 10, jj = j & 1023;
        const int code = jj >> 4, kg = jj & 15;  // consecutive tids -> contiguous k
        cbs[0][p][kg][code ^ (kg & 7)] =
            *(const s16x8*)((p ? cb_lo : cb_hi) + (long)code * 256 + kg * 8);
    }

    // ---- load B fragments once: full K=256 as 16 k-steps x {hi,lo} ----
    s16x8 zh[16], zl[16];
    {
        const unsigned* pz = ze_il + (long)tok * 256 + h * 8;
        #pragma unroll
        for (int ks = 0; ks < 16; ++ks) {
            uint4 u0 = *(const uint4*)(pz + ks * 16);
            uint4 u1 = *(const uint4*)(pz + ks * 16 + 4);
            unpack_il(u0, u1, zh[ks], zl[ks]);
        }
    }
    __syncthreads();

    float d1 = 3.4e38f, d2 = 3.4e38f;
    int   i1 = 0, i2 = 0;

    #pragma unroll 1
    for (int c = 0; c < 16; ++c) {               // 64-code chunks
        f32x16 acc[2] = {};                      // 2 code-tiles of 32

        #pragma unroll
        for (int kc = 0; kc < 2; ++kc) {         // 128-k halves; buf = kc
            const bool more = !(c == 15 && kc == 1);
            const int cn_ = c + kc, kn = kc ^ 1; // next stage coords

            // issue next-stage loads early
            s16x8 stg[8];
            if (more) {
                #pragma unroll
                for (int i = 0; i < 8; ++i) {
                    const int j = i * 256 + tid;
                    const int p = j >> 10, jj = j & 1023;
                    const int code = jj >> 4, kg = jj & 15;
                    stg[i] = *(const s16x8*)((p ? cb_lo : cb_hi)
                             + (long)(cn_ * 64 + code) * 256 + kn * 128 + kg * 8);
                }
            }

            // compute from cbs[kc]
            #pragma unroll
            for (int ks8 = 0; ks8 < 8; ++ks8) {
                const s16x8 zhv = zh[kc * 8 + ks8];
                const s16x8 zlv = zl[kc * 8 + ks8];
                const int kg = ks8 * 2 + h;
                #pragma unroll
                for (int nt = 0; nt < 2; ++nt) {
                    const int ci = (nt * 32 + li) ^ (kg & 7);
                    const s16x8 chv = cbs[kc][0][kg][ci];
                    const s16x8 clv = cbs[kc][1][kg][ci];
                    acc[nt] = __builtin_amdgcn_mfma_f32_32x32x16_bf16(clv, zhv, acc[nt], 0, 0, 0);
                    acc[nt] = __builtin_amdgcn_mfma_f32_32x32x16_bf16(chv, zlv, acc[nt], 0, 0, 0);
                    acc[nt] = __builtin_amdgcn_mfma_f32_32x32x16_bf16(chv, zhv, acc[nt], 0, 0, 0);
                }
            }

            // write staged regs to the other buffer
            if (more) {
                #pragma unroll
                for (int i = 0; i < 8; ++i) {
                    const int j = i * 256 + tid;
                    const int p = j >> 10, jj = j & 1023;
                    const int code = jj >> 4, kg = jj & 15;
                    cbs[kc ^ 1][p][kg][code ^ (kg & 7)] = stg[i];
                }
            }
            __syncthreads();
        }

        // ---- fold chunk into running top-2 (codes ascend per lane) ----
        #pragma unroll
        for (int nt = 0; nt < 2; ++nt) {
            const int cbase = c * 64 + nt * 32 + 4 * h;
            #pragma unroll
            for (int g = 0; g < 4; ++g) {
                float4 cn4 = *(const float4*)&cnorm[cbase + 8 * g];
                #pragma unroll
                for (int jj = 0; jj < 4; ++jj) {
                    float d = ((const float*)&cn4)[jj] - 2.0f * acc[nt][g * 4 + jj];
                    const int idx = cbase + 8 * g + jj;
                    if (d < d1)      { d2 = d1; i2 = i1; d1 = d; i1 = idx; }
                    else if (d < d2) { d2 = d; i2 = idx; }
                }
            }
        }
    }

    // ---- merge the two k-half lanes (codes 4h..: disjoint sets) ----
    {
        float od1 = __shfl_xor(d1, 32, 64);
        int   oi1 = __shfl_xor(i1, 32, 64);
        float od2 = __shfl_xor(d2, 32, 64);
        int   oi2 = __shfl_xor(i2, 32, 64);
        bool take = (od1 < d1) || (od1 == d1 && oi1 < i1);
        float w1 = take ? od1 : d1;  int wi1 = take ? oi1 : i1;
        float l1 = take ? d1 : od1;  int li1 = take ? i1 : oi1;
        float w2 = take ? od2 : d2;  int wi2 = take ? oi2 : i2;
        bool t2 = (l1 < w2) || (l1 == w2 && li1 < wi2);
        d1 = w1; i1 = wi1;
        d2 = t2 ? l1 : w2;
        i2 = t2 ? li1 : wi2;
    }

    const float rec = d1 + znorm[tok];
    if (lane < 32) {
        code_i[tok] = i1;
        code_f[tok] = (float)i1;
        if (d2 - d1 < TAU) {
            int slot = atomicAdd(flag_cnt, 1);
            if (slot < FLAG_CAP)
                flag_list[slot] = make_int4(tok, i1, i2, __float_as_int(rec));
        }
    }
    float lsum = (lane < 32) ? rec : 0.0f;
    #pragma unroll
    for (int off = 32; off; off >>= 1) lsum += __shfl_xor(lsum, off, 64);
    if (lane == 0)
        atomicAdd(loss_acc + (t0w >> 12), lsum);   // 32-tok tile never straddles a batch
}

// ---------------------------------------------------------------------------
// Exact fp32 refinement for near-tie tokens: recompute z_e row from z@w_down
// in fp32, re-decide best-of-two with first-index tie-break, patch loss.
// ---------------------------------------------------------------------------
__global__ __launch_bounds__(256) void refine_kernel(
        const float* __restrict__ z, const float* __restrict__ w_down,
        const float* __restrict__ cb, const int* __restrict__ flag_cnt,
        const int4* __restrict__ flag_list, int* __restrict__ code_i,
        float* __restrict__ code_f, float* __restrict__ loss_acc) {
    __shared__ float zrow[512];
    __shared__ float redA[4], redB[4];
    const int tid = threadIdx.x;
    int n = *flag_cnt;
    if (n > FLAG_CAP) n = FLAG_CAP;

    for (int it = blockIdx.x; it < n; it += gridDim.x) {
        const int4 f = flag_list[it];
        const int tok = f.x, ia = f.y, ib = f.z;
        __syncthreads();
        zrow[tid]       = z[(long)tok * 512 + tid];
        zrow[tid + 256] = z[(long)tok * 512 + 256 + tid];
        __syncthreads();

        float s = 0.0f;
        const float* wr = w_down + (long)tid * 512;
        #pragma unroll 4
        for (int k = 0; k < 512; k += 4) {
            float4 a = *(const float4*)(wr + k);
            s += a.x * zrow[k] + a.y * zrow[k + 1] + a.z * zrow[k + 2] + a.w * zrow[k + 3];
        }
        float da = s - cb[(long)ia * 256 + tid]; da *= da;
        float db = s - cb[(long)ib * 256 + tid]; db *= db;
        #pragma unroll
        for (int off = 32; off; off >>= 1) {
            da += __shfl_xor(da, off, 64);
            db += __shfl_xor(db, off, 64);
        }
        if ((tid & 63) == 0) { redA[tid >> 6] = da; redB[tid >> 6] = db; }
        __syncthreads();
        if (tid == 0) {
            float ea = redA[0] + redA[1] + redA[2] + redA[3];
            float eb = redB[0] + redB[1] + redB[2] + redB[3];
            float ebest = ea; int ibest = ia;
            if (eb < ea || (eb == ea && ib < ia)) { ebest = eb; ibest = ib; }
            if (ibest != ia) { code_i[tok] = ibest; code_f[tok] = (float)ibest; }
            atomicAdd(loss_acc + (tok >> 12), ebest - __int_as_float(f.w));
        }
    }
}

// ---------------------------------------------------------------------------
// Scale summed losses by 1/(4096*256) and write both loss outputs.
// ---------------------------------------------------------------------------
__global__ void finalize_kernel(const float* __restrict__ loss_acc,
                                float* __restrict__ out_losses) {
    int i = threadIdx.x;
    if (i < 16) {
        float v = loss_acc[i] * (1.0f / 1048576.0f);
        out_losses[i]      = v;   // commitment_loss
        out_losses[16 + i] = v;   // codebook_loss (same forward value)
    }
}

// ---------------------------------------------------------------------------
extern "C" void kernel_launch(void* const* d_in, const int* in_sizes, int n_in,
                              void* d_out, int out_size, void* d_ws, size_t ws_size,
                              hipStream_t stream) {
    const float* z      = (const float*)d_in[0];  // [16,4096,512]
    const float* cb     = (const float*)d_in[1];  // [1024,256]
    const float* w_down = (const float*)d_in[2];  // [256,512]
    const float* w_up   = (const float*)d_in[3];  // [512,256]

    float* out        = (float*)d_out;
    float* z_out      = out;                       // 33554432 floats
    float* out_losses = out + 33554432;            // 16 + 16 floats
    float* code_f     = out + 33554464;            // 65536 floats

    // z_e interleaved planes (hi<<16|lo, 64 MiB) live inside the not-yet-
    // written z_out region; fully consumed by argmin before gather writes.
    unsigned* ze_il = (unsigned*)d_out;

    char* ws = (char*)d_ws;
    unsigned short* cb_hi = (unsigned short*)(ws);             // 512 KiB
    unsigned short* cb_lo = (unsigned short*)(ws + 524288);    // 512 KiB
    unsigned short* wd_hi = (unsigned short*)(ws + 1048576);   // 256 KiB
    unsigned short* wd_lo = (unsigned short*)(ws + 1310720);   // 256 KiB
    int*   code_i    = (int*)  (ws + 1572864);                 // 256 KiB
    float* cnorm     = (float*)(ws + 1835008);                 // 4 KiB
    float* znorm     = (float*)(ws + 1839104);                 // 256 KiB
    int4*  flag_list = (int4*) (ws + 2101248);                 // 256 KiB
    float* cb_up     = (float*)(ws + 2363392);                 // 2 MiB
    float* loss_acc  = (float*)(ws + 4460544);                 // 64 B
    int*   flag_cnt  = (int*)  (ws + 4460608);                 // 4 B

    hipMemsetAsync(ws + 4460544, 0, 128, stream);

    // codebook row norms (fp32)
    rownorm_kernel<<<NCODES / 4, 256, 0, stream>>>(cb, cnorm);

    // bf16 hi/lo planes of codebook and w_down
    split_kernel<<<1024, 256, 0, stream>>>(cb, cb_hi, cb_lo, NCODES * D_E);
    split_kernel<<<512, 256, 0, stream>>>(w_down, wd_hi, wd_lo, D_E * D_IN);

    // exact fp32 up-projection of the whole codebook (replaces GEMM2)
    cb_up_kernel<<<NCODES / 4, 256, 0, stream>>>(cb, w_up, cb_up);

    // GEMM1 (MFMA 32x32 bf16x3, double-buffered LDS): z_e planes + znorm
    gemm_down_mfma_kernel<<<TOKS / 128, 256, 0, stream>>>(
        z, wd_hi, wd_lo, ze_il, znorm);

    // distances + argmin + losses (MFMA 32x32 bf16x3, swapped operands)
    argmin_mfma_kernel<<<TOKS / 128, 256, 0, stream>>>(
        ze_il, cb_hi, cb_lo, cnorm, znorm, code_i, code_f, loss_acc,
        flag_cnt, flag_list);

    // exact fp32 re-decision for near-tie tokens
    refine_kernel<<<256, 256, 0, stream>>>(z, w_down, cb, flag_cnt, flag_list,
                                           code_i, code_f, loss_acc);

    // z_out = cb_up[code] : pure gather, write-bound
    gather_kernel<<<TOKS * 512 / 4 / 1024, 256, 0, stream>>>(
        (const float4*)cb_up, code_i, (float4*)z_out);

    finalize_kernel<<<1, 64, 0, stream>>>(loss_acc, out_losses);
}